// Round 10
// baseline (333.298 us; speedup 1.0000x reference)
//
#include <hip/hip_runtime.h>
#include <hip/hip_fp16.h>
#include <math.h>

#define N_NODES 50000
#define N_EDGES 800000
#define N_TOT   850000   // E + N self-loops
#define EPS_BN  1e-5f
#define GAT_SLOPE 0.2f
#define ACT_SLOPE 0.01f
#define NBUCK   ((N_NODES + 255) / 256)   // 196 dst-buckets (256 dsts each)
#define BCAP    5120                       // slots per bucket (mean 4337)
#define K1_CH   4096                       // edges per bucket_append block
#define K1_NB   ((N_TOT + K1_CH - 1) / K1_CH)   // 208
#define GB64    ((N_NODES + 63) / 64)      // 782 GEMM row-blocks

typedef _Float16 half8_t __attribute__((ext_vector_type(8)));
typedef _Float16 half4_t __attribute__((ext_vector_type(4)));
typedef _Float16 half2_t __attribute__((ext_vector_type(2)));
typedef float    f32x4   __attribute__((ext_vector_type(4)));

__device__ __forceinline__ float wred_max(float x) {
#pragma unroll
    for (int m = 32; m; m >>= 1) x = fmaxf(x, __shfl_xor(x, m, 64));
    return x;
}
__device__ __forceinline__ float wred_sum(float x) {
#pragma unroll
    for (int m = 32; m; m >>= 1) x += __shfl_xor(x, m, 64);
    return x;
}
__device__ __forceinline__ int wred_sum_i(int x) {
#pragma unroll
    for (int m = 32; m; m >>= 1) x += __shfl_xor(x, m, 64);
    return x;
}

// fragment-major weight permutation: wtF[cb][ks][tt][lane][8] so a wave's
// B-fragment load (fixed cb,ks,tt; lane varies) is ONE contiguous 1KB read.
__device__ __forceinline__ void wf_perm(const float* __restrict__ W,
                                        _Float16* __restrict__ wt,
                                        int K, int C, int i) {
    int j   = i & 7;          // half within lane's 16B
    int l   = (i >> 3) & 63;  // lane
    int rest = i >> 9;        // (cb*KS + ks)*4 + tt
    int tt  = rest & 3;
    int ksf = rest >> 2;
    int KS  = K >> 5;
    int cb  = ksf / KS, ks = ksf - cb * KS;
    int k   = ks * 32 + (l >> 4) * 8 + j;
    int c   = cb * 64 + tt * 16 + (l & 15);
    wt[i] = (_Float16)W[k * C + c];
}

// ---- one-shot init: W fragment-major fp16, a-vec matvecs, counters zero ----
// gsum1/gsum2 are the global BN stat accumulators (relaxed atomicAdd targets);
// re-zeroed every graph replay here.
__global__ void init_misc(const float* __restrict__ W1, const float* __restrict__ W2,
                          const float* __restrict__ Wf, _Float16* __restrict__ wt1,
                          _Float16* __restrict__ wt2, _Float16* __restrict__ wtf,
                          int* __restrict__ bcnt,
                          float2* __restrict__ gsum1, float2* __restrict__ gsum2,
                          const float* __restrict__ as1, const float* __restrict__ ad1,
                          const float* __restrict__ as2, const float* __restrict__ ad2,
                          float* __restrict__ va1, float* __restrict__ vb1,
                          float* __restrict__ va2, float* __restrict__ vb2) {
    int i = blockIdx.x * 256 + threadIdx.x;
    if (i < NBUCK) bcnt[i] = 0;
    if (i < 128) gsum1[i] = make_float2(0.f, 0.f);
    if (i < 256) gsum2[i] = make_float2(0.f, 0.f);
    if (i < 8192) {                                  // W1: 64x128
        wf_perm(W1, wt1, 64, 128, i);
    } else if (i < 8192 + 32768) {                   // W2: 128x256
        wf_perm(W2, wt2, 128, 256, i - 8192);
    } else if (i < 8192 + 32768 + 65536) {           // Wf: 256x256
        wf_perm(Wf, wtf, 256, 256, i - 40960);
    } else if (i < 106496 + 384) {                   // a-vector matvecs
        int j = i - 106496;
        if (j < 64) {
            float s = 0.f;
            for (int c = 0; c < 128; ++c) s += W1[j * 128 + c] * as1[c];
            va1[j] = s;
        } else if (j < 128) {
            int k = j - 64; float s = 0.f;
            for (int c = 0; c < 128; ++c) s += W1[k * 128 + c] * ad1[c];
            vb1[k] = s;
        } else if (j < 256) {
            int k = j - 128; float s = 0.f;
            for (int c = 0; c < 256; ++c) s += W2[k * 256 + c] * as2[c];
            va2[k] = s;
        } else {
            int k = j - 256; float s = 0.f;
            for (int c = 0; c < 256; ++c) s += W2[k * 256 + c] * ad2[c];
            vb2[k] = s;
        }
    }
}

// ---- fused: bucketed-CSR pass 1 (blocks [0,K1_NB)) ∥ emb cast+dots (rest) ----
__global__ __launch_bounds__(256) void
append_emb(const int* __restrict__ ei, int* __restrict__ bcnt,
           unsigned* __restrict__ bedge,
           const float* __restrict__ emb, const float* __restrict__ va,
           const float* __restrict__ vb, _Float16* __restrict__ embh,
           float* __restrict__ e_n, float* __restrict__ f_n) {
    const int t = threadIdx.x;
    if ((int)blockIdx.x < K1_NB) {
        __shared__ int lcnt[NBUCK], lrank[NBUCK], gbase[NBUCK];
        const int base = blockIdx.x * K1_CH;
        const int nE = min(K1_CH, N_TOT - base);
        for (int i = t; i < NBUCK; i += 256) { lcnt[i] = 0; lrank[i] = 0; }
        __syncthreads();
        unsigned r[16];
#pragma unroll
        for (int j = 0; j < 16; ++j) {
            int i = t + j * 256;
            if (i < nE) {
                int e = base + i;
                int s, d;
                if (e < N_EDGES) { s = ei[e]; d = ei[N_EDGES + e]; }
                else { s = e - N_EDGES; d = s; }
                r[j] = ((unsigned)d << 16) | (unsigned)s;
                atomicAdd(&lcnt[d >> 8], 1);
            }
        }
        __syncthreads();
        if (t < NBUCK && lcnt[t] > 0) gbase[t] = atomicAdd(&bcnt[t], lcnt[t]);
        __syncthreads();
#pragma unroll
        for (int j = 0; j < 16; ++j) {
            int i = t + j * 256;
            if (i < nE) {
                unsigned v = r[j];
                int bk = v >> 24;                       // d>>8 (d < 65536)
                int gp = gbase[bk] + atomicAdd(&lrank[bk], 1);
                if (gp < BCAP) bedge[(size_t)bk * BCAP + gp] = v;
            }
        }
        return;
    }
    int rr = ((int)blockIdx.x - K1_NB) * 4 + (t >> 6);
    if (rr >= N_NODES) return;
    int l = t & 63;
    float v = emb[(size_t)rr * 64 + l];
    embh[(size_t)rr * 64 + l] = (_Float16)v;
    float pe = wred_sum(v * va[l]);
    float pf = wred_sum(v * vb[l]);
    if (l == 0) { e_n[rr] = pe; f_n[rr] = pf; }
}

// ---- bucketed CSR pass 2: per-bucket local CSR in LDS ----
__global__ __launch_bounds__(256) void
bucket_csr(const int* __restrict__ bcnt, const unsigned* __restrict__ bedge,
           int* __restrict__ ptr, int* __restrict__ srcs) {
    __shared__ int lcnt[256], lptr[256], lrank[256];
    __shared__ int wsum[4];
    __shared__ int sbase;
    const int b = blockIdx.x, t = threadIdx.x;
    lcnt[t] = 0; lrank[t] = 0;
    if (t < 64) {                       // exclusive prefix over buckets < b
        int s = 0;
        for (int j = t; j < b; j += 64) s += bcnt[j];
        s = wred_sum_i(s);
        if (t == 0) sbase = s;
    }
    __syncthreads();
    const int cnt = min(bcnt[b], BCAP);
    const int base0 = sbase;
    const unsigned* eb = bedge + (size_t)b * BCAP;
    for (int i = t; i < cnt; i += 256) atomicAdd(&lcnt[(eb[i] >> 16) & 255], 1);
    __syncthreads();
    int lane = t & 63, w = t >> 6;
    int v = lcnt[t];
    int x = v;
#pragma unroll
    for (int off = 1; off < 64; off <<= 1) {
        int y = __shfl_up(x, off, 64);
        if (lane >= off) x += y;
    }
    if (lane == 63) wsum[w] = x;
    __syncthreads();
    if (t == 0) {
        int s = 0;
#pragma unroll
        for (int i = 0; i < 4; ++i) { int tmp = wsum[i]; wsum[i] = s; s += tmp; }
    }
    __syncthreads();
    lptr[t] = x - v + wsum[w];
    __syncthreads();
    int d = b * 256 + t;
    if (d < N_NODES) ptr[d] = base0 + lptr[t];
    if (b == NBUCK - 1 && t == 0) ptr[N_NODES] = base0 + cnt;
    for (int i = t; i < cnt; i += 256) {
        unsigned v2 = eb[i];
        int dl = (v2 >> 16) & 255;
        int pos = base0 + lptr[dl] + atomicAdd(&lrank[dl], 1);
        srcs[pos] = (int)(v2 & 0xFFFFu);
    }
}

// ---- layer-2: z = lrelu(bn(out1)) stored once (fp16) + logit dots ----
// BN1 scale/shift derived on the fly from the atomically-accumulated gsum1
// (dispatch boundary after gemm1 = the visibility fence; no bn_coef pass).
__global__ __launch_bounds__(256) void
ef_dots(const _Float16* __restrict__ x, const float2* __restrict__ gsum,
        const float* __restrict__ gamma, const float* __restrict__ beta,
        const float* __restrict__ va, const float* __restrict__ vb,
        _Float16* __restrict__ z, float* __restrict__ e_n,
        float* __restrict__ f_n) {
    int r = blockIdx.x * 4 + (threadIdx.x >> 6);
    if (r >= N_NODES) return;
    int l = threadIdx.x & 63;
    int c = 2 * l;
    float2 s0 = gsum[c], s1 = gsum[c + 1];
    float mu0 = s0.x / N_NODES, mu1 = s1.x / N_NODES;
    float sc0 = gamma[c]     * rsqrtf(s0.y / N_NODES - mu0 * mu0 + EPS_BN);
    float sc1 = gamma[c + 1] * rsqrtf(s1.y / N_NODES - mu1 * mu1 + EPS_BN);
    float sh0 = beta[c]     - mu0 * sc0;
    float sh1 = beta[c + 1] - mu1 * sc1;
    half2_t hv = *(const half2_t*)&x[(size_t)r * 128 + c];
    float x0 = (float)hv[0] * sc0 + sh0;
    float x1 = (float)hv[1] * sc1 + sh1;
    x0 = x0 > 0.f ? x0 : ACT_SLOPE * x0;
    x1 = x1 > 0.f ? x1 : ACT_SLOPE * x1;
    half2_t zo = { (_Float16)x0, (_Float16)x1 };
    *(half2_t*)&z[(size_t)r * 128 + c] = zo;
    float pe = wred_sum(x0 * va[c] + x1 * va[c + 1]);
    float pf = wred_sum(x0 * vb[c] + x1 * vb[c + 1]);
    if (l == 0) { e_n[r] = pe; f_n[r] = pf; }
}

// ---- MFMA GEMM: out[n x C] = act(bn(x))[n x K] @ W[K x C] (+bias) ----
// 256 thr = 4 waves; 64 rows x CB cols per block; grid = rowblks x (C/CB).
// B from fragment-major wt (coalesced 1KB wave-loads), register dbuf.
// If BNIN: sc/sh for the K input columns computed in an LDS prologue from
// gsum_in (+gamma/beta), applied with lrelu during staging.
// If STATS: per-block column sum/sumsq reduced in LDS, then RELAXED global
// atomicAdd into gsum_out (no fences — round 8 showed in-kernel cross-XCD
// ordering costs an L2-invalidate per block; the next dispatch boundary is
// the fence).
template<int K, int C, int CB, typename OutT, bool STATS, bool BNIN>
__global__ __launch_bounds__(256) void
gemm_mfma(const _Float16* __restrict__ x, const _Float16* __restrict__ wt,
          const float* __restrict__ bias, OutT* __restrict__ out, int n,
          float2* __restrict__ gsum_out, const float2* __restrict__ gsum_in,
          const float* __restrict__ gamma, const float* __restrict__ beta) {
    constexpr int NW_C = CB / 64;      // col groups per block (1 or 2)
    constexpr int RT   = NW_C;         // row tiles per wave (rows/wave = 16*NW_C)
    constexpr int NCB  = C / CB;       // col blocks
    constexpr int KS   = K / 32;       // k-steps
    constexpr int LK   = K + 8;        // staging row stride (halves)
    constexpr int LCB  = CB + 4;       // cbuf row stride (floats, 16B-aligned)
    constexpr size_t SMB = ((size_t)64 * LK * 2 > (size_t)64 * LCB * 4)
                             ? (size_t)64 * LK * 2 : (size_t)64 * LCB * 4;
    __shared__ alignas(16) char smem[SMB];
    _Float16* xs  = (_Float16*)smem;
    float*   cbuf = (float*)smem;
    __shared__ float cs_sh[STATS ? CB : 1];
    __shared__ float cq_sh[STATS ? CB : 1];
    __shared__ float sc_in[BNIN ? K : 1];
    __shared__ float sh_in[BNIN ? K : 1];

    const int rb = blockIdx.x / NCB;
    const int cblk = blockIdx.x - rb * NCB;
    const int row0 = rb * 64;
    const int colB = cblk * CB;
    const int t = threadIdx.x;

    if (STATS) {
        for (int c = t; c < CB; c += 256) { cs_sh[c] = 0.f; cq_sh[c] = 0.f; }
    }
    if constexpr (BNIN) {
        for (int c = t; c < K; c += 256) {
            float2 sq = gsum_in[c];
            float mu = sq.x / N_NODES;
            float sc = gamma[c] * rsqrtf(sq.y / N_NODES - mu * mu + EPS_BN);
            sc_in[c] = sc;
            sh_in[c] = beta[c] - mu * sc;
        }
        __syncthreads();
    }

    // ---- stage x rows (optionally BN+lrelu fused) into LDS fp16 ----
    for (int i = t * 8; i < 64 * K; i += 256 * 8) {
        int r = i / K, c = i - (i / K) * K;
        half8_t v = {};
        if (row0 + r < n) v = *(const half8_t*)&x[(size_t)(row0 + r) * K + c];
        if constexpr (BNIN) {
#pragma unroll
            for (int j = 0; j < 8; ++j) {
                float f = (float)v[j] * sc_in[c + j] + sh_in[c + j];
                v[j] = (_Float16)(f > 0.f ? f : ACT_SLOPE * f);
            }
        }
        *(half8_t*)&xs[r * LK + c] = v;
    }
    __syncthreads();

    const int w = t >> 6, l = t & 63;
    const int l16 = l & 15, quad = l >> 4;
    const int lc0 = (w % NW_C) * 64;          // block-local col base of this wave
    const int gc0 = colB + lc0;               // global col base
    const int mbase = (w / NW_C) * (16 * NW_C);
    // fragment-major base for this wave's col-block, lane-contiguous
    const _Float16* wtw = wt + (size_t)(gc0 >> 6) * KS * 4 * 512 + l * 8;

    f32x4 acc[RT][4] = {};
    half8_t bA[4], bB[4];
    auto loadB = [&](int k0, half8_t* bf) {
        const _Float16* p = wtw + (size_t)(k0 >> 5) * 4 * 512;
#pragma unroll
        for (int tt = 0; tt < 4; ++tt)
            bf[tt] = *(const half8_t*)&p[tt * 512];
    };
    auto doMM = [&](int k0, half8_t* bf) {
        half8_t a[RT];
#pragma unroll
        for (int rt = 0; rt < RT; ++rt)
            a[rt] = *(const half8_t*)&xs[(mbase + rt * 16 + l16) * LK + k0 + quad * 8];
#pragma unroll
        for (int rt = 0; rt < RT; ++rt)
#pragma unroll
            for (int tt = 0; tt < 4; ++tt)
                acc[rt][tt] = __builtin_amdgcn_mfma_f32_16x16x32_f16(a[rt], bf[tt],
                                                                     acc[rt][tt], 0, 0, 0);
    };
    loadB(0, bA);
#pragma unroll
    for (int k0 = 0; k0 < K; k0 += 64) {
        loadB(k0 + 32, bB);
        doMM(k0, bA);
        if (k0 + 64 < K) loadB(k0 + 64, bA);
        doMM(k0 + 32, bB);
    }

    // ---- epilogue: acc -> cbuf (+bias), stats from registers ----
    __syncthreads();   // xs dead (a-frags consumed), cbuf takes over smem
#pragma unroll
    for (int rt = 0; rt < RT; ++rt) {
#pragma unroll
        for (int tt = 0; tt < 4; ++tt) {
            int lcol = lc0 + tt * 16 + l16;
            float bb = bias ? bias[colB + lcol] : 0.f;
            float s = 0.f, q = 0.f;
#pragma unroll
            for (int i = 0; i < 4; ++i) {
                int lrow = mbase + rt * 16 + quad * 4 + i;
                float v = acc[rt][tt][i] + bb;
                cbuf[lrow * LCB + lcol] = v;
                if (STATS && row0 + lrow < n) { s += v; q += v * v; }
            }
            if constexpr (STATS) {
                s += __shfl_xor(s, 16, 64); s += __shfl_xor(s, 32, 64);
                q += __shfl_xor(q, 16, 64); q += __shfl_xor(q, 32, 64);
                if (quad == 0) {
                    atomicAdd(&cs_sh[lcol], s);
                    atomicAdd(&cq_sh[lcol], q);
                }
            }
        }
    }
    __syncthreads();
    if constexpr (STATS) {
        // relaxed device-scope atomics; ≤ GB64 adds per address, no ordering
        for (int c = t; c < CB; c += 256) {
            atomicAdd(&gsum_out[colB + c].x, cs_sh[c]);
            atomicAdd(&gsum_out[colB + c].y, cq_sh[c]);
        }
    }
    // ---- coalesced row-major store ----
    for (int i = t * 4; i < 64 * CB; i += 256 * 4) {
        int r = i / CB, c = i - (i / CB) * CB;
        if (row0 + r < n) {
            float4 v4 = *(const float4*)&cbuf[r * LCB + c];
            if constexpr (__is_same(OutT, float)) {
                *(float4*)&out[(size_t)(row0 + r) * C + colB + c] = v4;
            } else {
                half4_t h4 = { (_Float16)v4.x, (_Float16)v4.y,
                               (_Float16)v4.z, (_Float16)v4.w };
                *(half4_t*)&out[(size_t)(row0 + r) * C + colB + c] = h4;
            }
        }
    }
}

// ---- fused softmax + weighted gather over the GEMM *input* rows ----
template<int C>
__global__ __launch_bounds__(256) void
attn_aggregate(const _Float16* __restrict__ h, const int* __restrict__ srcs,
               const int* __restrict__ ptr, const float* __restrict__ e_n,
               const float* __restrict__ f_n, _Float16* __restrict__ out) {
    constexpr int RL = C / 8;          // lanes per row: 8 (C=64) or 16 (C=128)
    constexpr int G  = 64 / RL;        // row groups per wave: 8 or 4
    int d = blockIdx.x * 4 + (threadIdx.x >> 6);
    if (d >= N_NODES) return;
    int l  = threadIdx.x & 63;
    int b0 = ptr[d], b1 = ptr[d + 1];
    int deg = b1 - b0;
    float fd = f_n[d];
    const int g  = l / RL;
    const int cl = l % RL;
    float acc[8] = {0.f, 0.f, 0.f, 0.f, 0.f, 0.f, 0.f, 0.f};

    if (deg <= 64) {
        int sj = 0; float lg = -1e30f;
        if (l < deg) {
            sj = srcs[b0 + l];
            float v = e_n[sj] + fd;
            lg = v > 0.f ? v : GAT_SLOPE * v;
        }
        float m  = wred_max(lg);
        float e0 = (l < deg) ? __expf(lg - m) : 0.f;
        float ex = e0 / wred_sum(e0);

        int jj = 0;
        for (; jj + 4 * G <= deg; jj += 4 * G) {     // 4 loads in flight / group
            float wk[4]; int sk[4];
#pragma unroll
            for (int k = 0; k < 4; ++k) {
                int j = jj + k * G + g;
                wk[k] = __shfl(ex, j, 64);
                sk[k] = __shfl(sj, j, 64);
            }
            half8_t v[4];
#pragma unroll
            for (int k = 0; k < 4; ++k)
                v[k] = *(const half8_t*)&h[(size_t)sk[k] * C + cl * 8];
#pragma unroll
            for (int k = 0; k < 4; ++k)
#pragma unroll
                for (int i = 0; i < 8; ++i)
                    acc[i] += wk[k] * (float)v[k][i];
        }
        for (; jj + 2 * G <= deg; jj += 2 * G) {
            float w1 = __shfl(ex, jj + g, 64);
            int   s1 = __shfl(sj, jj + g, 64);
            float w2 = __shfl(ex, jj + G + g, 64);
            int   s2 = __shfl(sj, jj + G + g, 64);
            half8_t v1 = *(const half8_t*)&h[(size_t)s1 * C + cl * 8];
            half8_t v2 = *(const half8_t*)&h[(size_t)s2 * C + cl * 8];
#pragma unroll
            for (int i = 0; i < 8; ++i)
                acc[i] += w1 * (float)v1[i] + w2 * (float)v2[i];
        }
        for (; jj < deg; jj += G) {                  // exact tail
            int j = jj + g;
            float wk = __shfl(ex, j, 64);
            int   sk = __shfl(sj, j, 64);
            if (j < deg) {
                half8_t v = *(const half8_t*)&h[(size_t)sk * C + cl * 8];
#pragma unroll
                for (int i = 0; i < 8; ++i) acc[i] += wk * (float)v[i];
            }
        }
    } else {
        float m_l = -1e30f, den_l = 0.f;
        for (int j = b0 + l; j < b1; j += 64) {
            float lg = e_n[srcs[j]] + fd;
            lg = lg > 0.f ? lg : GAT_SLOPE * lg;
            float nm = fmaxf(m_l, lg);
            den_l = den_l * __expf(m_l - nm) + __expf(lg - nm);
            m_l = nm;
        }
        float m = wred_max(m_l);
        float inv = 1.f / wred_sum(den_l * __expf(m_l - m));
        for (int c0 = b0; c0 < b1; c0 += 64) {
            int jl = c0 + l;
            int sj = 0; float ex = 0.f;
            if (jl < b1) {
                sj = srcs[jl];
                float lg = e_n[sj] + fd;
                lg = lg > 0.f ? lg : GAT_SLOPE * lg;
                ex = __expf(lg - m) * inv;
            }
            int nE = min(64, b1 - c0);
            for (int jj = 0; jj < nE; jj += 2 * G) {
                int j1 = jj + g, j2 = jj + G + g;
                float w1 = __shfl(ex, j1, 64);
                int   s1 = __shfl(sj, j1, 64);
                float w2 = __shfl(ex, j2, 64);
                int   s2 = __shfl(sj, j2, 64);
                half8_t v1 = *(const half8_t*)&h[(size_t)s1 * C + cl * 8];
                half8_t v2 = *(const half8_t*)&h[(size_t)s2 * C + cl * 8];
#pragma unroll
                for (int i = 0; i < 8; ++i)
                    acc[i] += w1 * (float)v1[i] + w2 * (float)v2[i];
            }
        }
    }
#pragma unroll
    for (int mm = RL; mm < 64; mm <<= 1)
#pragma unroll
        for (int i = 0; i < 8; ++i) acc[i] += __shfl_xor(acc[i], mm, 64);
    if (g == 0) {
        int c = cl * 8;
        half8_t o;
#pragma unroll
        for (int i = 0; i < 8; ++i) o[i] = (_Float16)acc[i];
        *(half8_t*)&out[(size_t)d * C + c] = o;
    }
}

extern "C" void kernel_launch(void* const* d_in, const int* in_sizes, int n_in,
                              void* d_out, int out_size, void* d_ws, size_t ws_size,
                              hipStream_t stream) {
    const float* emb  = (const float*)d_in[0];
    const int*   ei   = (const int*)  d_in[1];
    const float* W1   = (const float*)d_in[2];
    const float* as1  = (const float*)d_in[3];
    const float* ad1  = (const float*)d_in[4];
    const float* b1   = (const float*)d_in[5];
    const float* g1   = (const float*)d_in[6];
    const float* be1  = (const float*)d_in[7];
    const float* W2   = (const float*)d_in[8];
    const float* as2  = (const float*)d_in[9];
    const float* ad2  = (const float*)d_in[10];
    const float* b2   = (const float*)d_in[11];
    const float* g2   = (const float*)d_in[12];
    const float* be2  = (const float*)d_in[13];
    const float* Wf   = (const float*)d_in[14];
    const float* bf   = (const float*)d_in[15];
    float* out = (float*)d_out;

    char* w = (char*)d_ws;
    auto alloc = [&](size_t bytes) {
        char* p = w;
        w += (bytes + 255) & ~(size_t)255;
        return (void*)p;
    };
    // embh and agg1 are contiguous (each 6.4MB, 256B-aligned) — together they
    // are reused as z1h (12.8MB) after both are dead.
    _Float16* embh = (_Float16*)alloc((size_t)N_NODES * 64 * 2);   // emb fp16
    _Float16* agg1 = (_Float16*)alloc((size_t)N_NODES * 64 * 2);   // layer-1 aggregate
    _Float16* out1 = (_Float16*)alloc((size_t)N_NODES * 128 * 2);  // agg1 @ W1 + b1
    _Float16* agg2 = (_Float16*)alloc((size_t)N_NODES * 128 * 2);  // layer-2 aggregate
    _Float16* out2 = (_Float16*)alloc((size_t)N_NODES * 256 * 2);  // agg2 @ W2 + b2
    _Float16* z1h  = embh;                       // alias: lrelu(bn(out1)), 12.8MB
    unsigned* bedge = (unsigned*)out2;           // alias: bucket edges (4MB), dead
                                                 // before out2 is written
    float*  e_n  = (float*) alloc((size_t)N_NODES * 4);
    float*  f_n  = (float*) alloc((size_t)N_NODES * 4);
    int*    srcs = (int*)   alloc((size_t)N_TOT * 4);
    int*    bcnt = (int*)   alloc((size_t)NBUCK * 4);
    int*    ptr  = (int*)   alloc((size_t)(N_NODES + 1) * 4);
    float2* gsum1 = (float2*)alloc(128 * 8);     // BN1 atomic accumulators
    float2* gsum2 = (float2*)alloc(256 * 8);     // BN2 atomic accumulators
    float*  va1  = (float*) alloc(64 * 4);
    float*  vb1  = (float*) alloc(64 * 4);
    float*  va2  = (float*) alloc(128 * 4);
    float*  vb2  = (float*) alloc(128 * 4);
    _Float16* wt1 = (_Float16*)alloc((size_t)64 * 128 * 2);
    _Float16* wt2 = (_Float16*)alloc((size_t)128 * 256 * 2);
    _Float16* wtf = (_Float16*)alloc((size_t)256 * 256 * 2);

    const int RW4 = (N_NODES + 3) / 4;   // wave-per-row grids

    // 1) init: weight fragment-major + a-vec matvecs + counters/gsum zero
    init_misc<<<(106496 + 384 + 255) / 256, 256, 0, stream>>>(
        W1, W2, Wf, wt1, wt2, wtf, bcnt, gsum1, gsum2,
        as1, ad1, as2, ad2, va1, vb1, va2, vb2);

    // 2) fused: bucket append (single-pass) ∥ emb cast + layer-1 logits
    append_emb<<<K1_NB + RW4, 256, 0, stream>>>(
        ei, bcnt, bedge, emb, va1, vb1, embh, e_n, f_n);

    // 3) per-bucket CSR
    bucket_csr<<<NBUCK, 256, 0, stream>>>(bcnt, bedge, ptr, srcs);

    // 4) layer-1 aggregate (128B rows)
    attn_aggregate<64><<<RW4, 256, 0, stream>>>(embh, srcs, ptr, e_n, f_n, agg1);

    // 5) GEMM 64->128, BN1 stats -> gsum1 (relaxed atomics)
    gemm_mfma<64, 128, 128, _Float16, true, false><<<GB64, 256, 0, stream>>>(
        agg1, wt1, b1, out1, N_NODES, gsum1, nullptr, nullptr, nullptr);

    // 6) z1 = lrelu(bn1(out1)) (coefs from gsum1 on the fly) + layer-2 logits
    ef_dots<<<RW4, 256, 0, stream>>>(out1, gsum1, g1, be1, va2, vb2, z1h, e_n, f_n);

    // 7) layer-2 aggregate (256B rows)
    attn_aggregate<128><<<RW4, 256, 0, stream>>>(z1h, srcs, ptr, e_n, f_n, agg2);

    // 8) GEMM 128->256, BN2 stats -> gsum2 (relaxed atomics)
    gemm_mfma<128, 256, 128, _Float16, true, false><<<GB64 * 2, 256, 0, stream>>>(
        agg2, wt2, b2, out2, N_NODES, gsum2, nullptr, nullptr, nullptr);

    // 9) final linear 256->256, BN2+lrelu from gsum2 in LDS prologue
    gemm_mfma<256, 256, 128, float, false, true><<<GB64 * 2, 256, 0, stream>>>(
        out2, wtf, bf, out, N_NODES, nullptr, gsum2, g2, be2);
}

// Round 11
// 280.923 us; speedup vs baseline: 1.1864x; 1.1864x over previous
//
#include <hip/hip_runtime.h>
#include <hip/hip_fp16.h>
#include <math.h>

#define N_NODES 50000
#define N_EDGES 800000
#define N_TOT   850000   // E + N self-loops
#define EPS_BN  1e-5f
#define GAT_SLOPE 0.2f
#define ACT_SLOPE 0.01f
#define NBUCK   ((N_NODES + 255) / 256)   // 196 dst-buckets (256 dsts each)
#define BCAP    5120                       // slots per bucket (mean 4337)
#define K1_CH   4096                       // edges per bucket_append block
#define K1_NB   ((N_TOT + K1_CH - 1) / K1_CH)   // 208
#define GB64    ((N_NODES + 63) / 64)      // 782 GEMM row-blocks
#define NREP    8                          // BN accumulator replicas (depth limit)

typedef _Float16 half8_t __attribute__((ext_vector_type(8)));
typedef _Float16 half4_t __attribute__((ext_vector_type(4)));
typedef _Float16 half2_t __attribute__((ext_vector_type(2)));
typedef float    f32x4   __attribute__((ext_vector_type(4)));

__device__ __forceinline__ float wred_max(float x) {
#pragma unroll
    for (int m = 32; m; m >>= 1) x = fmaxf(x, __shfl_xor(x, m, 64));
    return x;
}
__device__ __forceinline__ float wred_sum(float x) {
#pragma unroll
    for (int m = 32; m; m >>= 1) x += __shfl_xor(x, m, 64);
    return x;
}
__device__ __forceinline__ int wred_sum_i(int x) {
#pragma unroll
    for (int m = 32; m; m >>= 1) x += __shfl_xor(x, m, 64);
    return x;
}

// fragment-major weight permutation: wtF[cb][ks][tt][lane][8] so a wave's
// B-fragment load (fixed cb,ks,tt; lane varies) is ONE contiguous 1KB read.
__device__ __forceinline__ void wf_perm(const float* __restrict__ W,
                                        _Float16* __restrict__ wt,
                                        int K, int C, int i) {
    int j   = i & 7;          // half within lane's 16B
    int l   = (i >> 3) & 63;  // lane
    int rest = i >> 9;        // (cb*KS + ks)*4 + tt
    int tt  = rest & 3;
    int ksf = rest >> 2;
    int KS  = K >> 5;
    int cb  = ksf / KS, ks = ksf - cb * KS;
    int k   = ks * 32 + (l >> 4) * 8 + j;
    int c   = cb * 64 + tt * 16 + (l & 15);
    wt[i] = (_Float16)W[k * C + c];
}

// ---- one-shot init: W fragment-major fp16, a-vec matvecs, counters zero ----
// gsum1/gsum2: replicated BN accumulators [NREP][C], re-zeroed every replay.
__global__ void init_misc(const float* __restrict__ W1, const float* __restrict__ W2,
                          const float* __restrict__ Wf, _Float16* __restrict__ wt1,
                          _Float16* __restrict__ wt2, _Float16* __restrict__ wtf,
                          int* __restrict__ bcnt,
                          float2* __restrict__ gsum1, float2* __restrict__ gsum2,
                          const float* __restrict__ as1, const float* __restrict__ ad1,
                          const float* __restrict__ as2, const float* __restrict__ ad2,
                          float* __restrict__ va1, float* __restrict__ vb1,
                          float* __restrict__ va2, float* __restrict__ vb2) {
    int i = blockIdx.x * 256 + threadIdx.x;
    if (i < NBUCK) bcnt[i] = 0;
    if (i < NREP * 128) gsum1[i] = make_float2(0.f, 0.f);
    if (i < NREP * 256) gsum2[i] = make_float2(0.f, 0.f);
    if (i < 8192) {                                  // W1: 64x128
        wf_perm(W1, wt1, 64, 128, i);
    } else if (i < 8192 + 32768) {                   // W2: 128x256
        wf_perm(W2, wt2, 128, 256, i - 8192);
    } else if (i < 8192 + 32768 + 65536) {           // Wf: 256x256
        wf_perm(Wf, wtf, 256, 256, i - 40960);
    } else if (i < 106496 + 384) {                   // a-vector matvecs
        int j = i - 106496;
        if (j < 64) {
            float s = 0.f;
            for (int c = 0; c < 128; ++c) s += W1[j * 128 + c] * as1[c];
            va1[j] = s;
        } else if (j < 128) {
            int k = j - 64; float s = 0.f;
            for (int c = 0; c < 128; ++c) s += W1[k * 128 + c] * ad1[c];
            vb1[k] = s;
        } else if (j < 256) {
            int k = j - 128; float s = 0.f;
            for (int c = 0; c < 256; ++c) s += W2[k * 256 + c] * as2[c];
            va2[k] = s;
        } else {
            int k = j - 256; float s = 0.f;
            for (int c = 0; c < 256; ++c) s += W2[k * 256 + c] * ad2[c];
            vb2[k] = s;
        }
    }
}

// ---- fused: bucketed-CSR pass 1 (blocks [0,K1_NB)) ∥ emb cast+dots (rest) ----
__global__ __launch_bounds__(256) void
append_emb(const int* __restrict__ ei, int* __restrict__ bcnt,
           unsigned* __restrict__ bedge,
           const float* __restrict__ emb, const float* __restrict__ va,
           const float* __restrict__ vb, _Float16* __restrict__ embh,
           float* __restrict__ e_n, float* __restrict__ f_n) {
    const int t = threadIdx.x;
    if ((int)blockIdx.x < K1_NB) {
        __shared__ int lcnt[NBUCK], lrank[NBUCK], gbase[NBUCK];
        const int base = blockIdx.x * K1_CH;
        const int nE = min(K1_CH, N_TOT - base);
        for (int i = t; i < NBUCK; i += 256) { lcnt[i] = 0; lrank[i] = 0; }
        __syncthreads();
        unsigned r[16];
#pragma unroll
        for (int j = 0; j < 16; ++j) {
            int i = t + j * 256;
            if (i < nE) {
                int e = base + i;
                int s, d;
                if (e < N_EDGES) { s = ei[e]; d = ei[N_EDGES + e]; }
                else { s = e - N_EDGES; d = s; }
                r[j] = ((unsigned)d << 16) | (unsigned)s;
                atomicAdd(&lcnt[d >> 8], 1);
            }
        }
        __syncthreads();
        if (t < NBUCK && lcnt[t] > 0) gbase[t] = atomicAdd(&bcnt[t], lcnt[t]);
        __syncthreads();
#pragma unroll
        for (int j = 0; j < 16; ++j) {
            int i = t + j * 256;
            if (i < nE) {
                unsigned v = r[j];
                int bk = v >> 24;                       // d>>8 (d < 65536)
                int gp = gbase[bk] + atomicAdd(&lrank[bk], 1);
                if (gp < BCAP) bedge[(size_t)bk * BCAP + gp] = v;
            }
        }
        return;
    }
    int rr = ((int)blockIdx.x - K1_NB) * 4 + (t >> 6);
    if (rr >= N_NODES) return;
    int l = t & 63;
    float v = emb[(size_t)rr * 64 + l];
    embh[(size_t)rr * 64 + l] = (_Float16)v;
    float pe = wred_sum(v * va[l]);
    float pf = wred_sum(v * vb[l]);
    if (l == 0) { e_n[rr] = pe; f_n[rr] = pf; }
}

// ---- bucketed CSR pass 2: per-bucket local CSR in LDS ----
__global__ __launch_bounds__(256) void
bucket_csr(const int* __restrict__ bcnt, const unsigned* __restrict__ bedge,
           int* __restrict__ ptr, int* __restrict__ srcs) {
    __shared__ int lcnt[256], lptr[256], lrank[256];
    __shared__ int wsum[4];
    __shared__ int sbase;
    const int b = blockIdx.x, t = threadIdx.x;
    lcnt[t] = 0; lrank[t] = 0;
    if (t < 64) {                       // exclusive prefix over buckets < b
        int s = 0;
        for (int j = t; j < b; j += 64) s += bcnt[j];
        s = wred_sum_i(s);
        if (t == 0) sbase = s;
    }
    __syncthreads();
    const int cnt = min(bcnt[b], BCAP);
    const int base0 = sbase;
    const unsigned* eb = bedge + (size_t)b * BCAP;
    for (int i = t; i < cnt; i += 256) atomicAdd(&lcnt[(eb[i] >> 16) & 255], 1);
    __syncthreads();
    int lane = t & 63, w = t >> 6;
    int v = lcnt[t];
    int x = v;
#pragma unroll
    for (int off = 1; off < 64; off <<= 1) {
        int y = __shfl_up(x, off, 64);
        if (lane >= off) x += y;
    }
    if (lane == 63) wsum[w] = x;
    __syncthreads();
    if (t == 0) {
        int s = 0;
#pragma unroll
        for (int i = 0; i < 4; ++i) { int tmp = wsum[i]; wsum[i] = s; s += tmp; }
    }
    __syncthreads();
    lptr[t] = x - v + wsum[w];
    __syncthreads();
    int d = b * 256 + t;
    if (d < N_NODES) ptr[d] = base0 + lptr[t];
    if (b == NBUCK - 1 && t == 0) ptr[N_NODES] = base0 + cnt;
    for (int i = t; i < cnt; i += 256) {
        unsigned v2 = eb[i];
        int dl = (v2 >> 16) & 255;
        int pos = base0 + lptr[dl] + atomicAdd(&lrank[dl], 1);
        srcs[pos] = (int)(v2 & 0xFFFFu);
    }
}

// ---- layer-2: z = lrelu(bn(out1)) stored once (fp16) + logit dots ----
// BN1 coefs from the NREP-replicated gsum1 reduced per-lane (8 L2-hot float4
// loads); the gemm1->ef_dots dispatch boundary is the visibility fence.
__global__ __launch_bounds__(256) void
ef_dots(const _Float16* __restrict__ x, const float2* __restrict__ gsum,
        const float* __restrict__ gamma, const float* __restrict__ beta,
        const float* __restrict__ va, const float* __restrict__ vb,
        _Float16* __restrict__ z, float* __restrict__ e_n,
        float* __restrict__ f_n) {
    int r = blockIdx.x * 4 + (threadIdx.x >> 6);
    if (r >= N_NODES) return;
    int l = threadIdx.x & 63;
    int c = 2 * l;
    float4 sq = make_float4(0.f, 0.f, 0.f, 0.f);   // (s0,q0,s1,q1)
#pragma unroll
    for (int rep = 0; rep < NREP; ++rep) {
        float4 p = *(const float4*)&gsum[rep * 128 + c];
        sq.x += p.x; sq.y += p.y; sq.z += p.z; sq.w += p.w;
    }
    float mu0 = sq.x / N_NODES, mu1 = sq.z / N_NODES;
    float sc0 = gamma[c]     * rsqrtf(sq.y / N_NODES - mu0 * mu0 + EPS_BN);
    float sc1 = gamma[c + 1] * rsqrtf(sq.w / N_NODES - mu1 * mu1 + EPS_BN);
    float sh0 = beta[c]     - mu0 * sc0;
    float sh1 = beta[c + 1] - mu1 * sc1;
    half2_t hv = *(const half2_t*)&x[(size_t)r * 128 + c];
    float x0 = (float)hv[0] * sc0 + sh0;
    float x1 = (float)hv[1] * sc1 + sh1;
    x0 = x0 > 0.f ? x0 : ACT_SLOPE * x0;
    x1 = x1 > 0.f ? x1 : ACT_SLOPE * x1;
    half2_t zo = { (_Float16)x0, (_Float16)x1 };
    *(half2_t*)&z[(size_t)r * 128 + c] = zo;
    float pe = wred_sum(x0 * va[c] + x1 * va[c + 1]);
    float pf = wred_sum(x0 * vb[c] + x1 * vb[c + 1]);
    if (l == 0) { e_n[r] = pe; f_n[r] = pf; }
}

// ---- MFMA GEMM: out[n x C] = act(bn(x))[n x K] @ W[K x C] (+bias) ----
// 256 thr = 4 waves; 64 rows x CB cols per block; grid = rowblks x (C/CB).
// B from fragment-major wt (coalesced 1KB wave-loads), register dbuf.
// If BNIN: sc/sh for the K input cols from NREP-replica gsum_in reduced in an
// LDS prologue, applied with lrelu during staging.
// If STATS: per-block column sum/sumsq LDS-reduced, then relaxed atomicAdd
// into gsum_out[rb%NREP][*]. Replication caps per-cache-line atomic depth at
// ~GB64/NREP ≈ 100 (round 10: 782-deep on 32 lines cost ~3ns/atomic ≈ 38 µs).
template<int K, int C, int CB, typename OutT, bool STATS, bool BNIN>
__global__ __launch_bounds__(256) void
gemm_mfma(const _Float16* __restrict__ x, const _Float16* __restrict__ wt,
          const float* __restrict__ bias, OutT* __restrict__ out, int n,
          float2* __restrict__ gsum_out, const float2* __restrict__ gsum_in,
          const float* __restrict__ gamma, const float* __restrict__ beta) {
    constexpr int NW_C = CB / 64;      // col groups per block (1 or 2)
    constexpr int RT   = NW_C;         // row tiles per wave (rows/wave = 16*NW_C)
    constexpr int NCB  = C / CB;       // col blocks
    constexpr int KS   = K / 32;       // k-steps
    constexpr int LK   = K + 8;        // staging row stride (halves)
    constexpr int LCB  = CB + 4;       // cbuf row stride (floats, 16B-aligned)
    constexpr size_t SMB = ((size_t)64 * LK * 2 > (size_t)64 * LCB * 4)
                             ? (size_t)64 * LK * 2 : (size_t)64 * LCB * 4;
    __shared__ alignas(16) char smem[SMB];
    _Float16* xs  = (_Float16*)smem;
    float*   cbuf = (float*)smem;
    __shared__ float cs_sh[STATS ? CB : 1];
    __shared__ float cq_sh[STATS ? CB : 1];
    __shared__ float sc_in[BNIN ? K : 1];
    __shared__ float sh_in[BNIN ? K : 1];

    const int rb = blockIdx.x / NCB;
    const int cblk = blockIdx.x - rb * NCB;
    const int row0 = rb * 64;
    const int colB = cblk * CB;
    const int t = threadIdx.x;

    if (STATS) {
        for (int c = t; c < CB; c += 256) { cs_sh[c] = 0.f; cq_sh[c] = 0.f; }
    }
    if constexpr (BNIN) {
        for (int c = t; c < K; c += 256) {
            float s = 0.f, q = 0.f;
#pragma unroll
            for (int rep = 0; rep < NREP; ++rep) {
                float2 p = gsum_in[rep * K + c];
                s += p.x; q += p.y;
            }
            float mu = s / N_NODES;
            float sc = gamma[c] * rsqrtf(q / N_NODES - mu * mu + EPS_BN);
            sc_in[c] = sc;
            sh_in[c] = beta[c] - mu * sc;
        }
        __syncthreads();
    }

    // ---- stage x rows (optionally BN+lrelu fused) into LDS fp16 ----
    for (int i = t * 8; i < 64 * K; i += 256 * 8) {
        int r = i / K, c = i - (i / K) * K;
        half8_t v = {};
        if (row0 + r < n) v = *(const half8_t*)&x[(size_t)(row0 + r) * K + c];
        if constexpr (BNIN) {
#pragma unroll
            for (int j = 0; j < 8; ++j) {
                float f = (float)v[j] * sc_in[c + j] + sh_in[c + j];
                v[j] = (_Float16)(f > 0.f ? f : ACT_SLOPE * f);
            }
        }
        *(half8_t*)&xs[r * LK + c] = v;
    }
    __syncthreads();

    const int w = t >> 6, l = t & 63;
    const int l16 = l & 15, quad = l >> 4;
    const int lc0 = (w % NW_C) * 64;          // block-local col base of this wave
    const int gc0 = colB + lc0;               // global col base
    const int mbase = (w / NW_C) * (16 * NW_C);
    // fragment-major base for this wave's col-block, lane-contiguous
    const _Float16* wtw = wt + (size_t)(gc0 >> 6) * KS * 4 * 512 + l * 8;

    f32x4 acc[RT][4] = {};
    half8_t bA[4], bB[4];
    auto loadB = [&](int k0, half8_t* bf) {
        const _Float16* p = wtw + (size_t)(k0 >> 5) * 4 * 512;
#pragma unroll
        for (int tt = 0; tt < 4; ++tt)
            bf[tt] = *(const half8_t*)&p[tt * 512];
    };
    auto doMM = [&](int k0, half8_t* bf) {
        half8_t a[RT];
#pragma unroll
        for (int rt = 0; rt < RT; ++rt)
            a[rt] = *(const half8_t*)&xs[(mbase + rt * 16 + l16) * LK + k0 + quad * 8];
#pragma unroll
        for (int rt = 0; rt < RT; ++rt)
#pragma unroll
            for (int tt = 0; tt < 4; ++tt)
                acc[rt][tt] = __builtin_amdgcn_mfma_f32_16x16x32_f16(a[rt], bf[tt],
                                                                     acc[rt][tt], 0, 0, 0);
    };
    loadB(0, bA);
#pragma unroll
    for (int k0 = 0; k0 < K; k0 += 64) {
        loadB(k0 + 32, bB);
        doMM(k0, bA);
        if (k0 + 64 < K) loadB(k0 + 64, bA);
        doMM(k0 + 32, bB);
    }

    // ---- epilogue: acc -> cbuf (+bias), stats from registers ----
    __syncthreads();   // xs dead (a-frags consumed), cbuf takes over smem
#pragma unroll
    for (int rt = 0; rt < RT; ++rt) {
#pragma unroll
        for (int tt = 0; tt < 4; ++tt) {
            int lcol = lc0 + tt * 16 + l16;
            float bb = bias ? bias[colB + lcol] : 0.f;
            float s = 0.f, q = 0.f;
#pragma unroll
            for (int i = 0; i < 4; ++i) {
                int lrow = mbase + rt * 16 + quad * 4 + i;
                float v = acc[rt][tt][i] + bb;
                cbuf[lrow * LCB + lcol] = v;
                if (STATS && row0 + lrow < n) { s += v; q += v * v; }
            }
            if constexpr (STATS) {
                s += __shfl_xor(s, 16, 64); s += __shfl_xor(s, 32, 64);
                q += __shfl_xor(q, 16, 64); q += __shfl_xor(q, 32, 64);
                if (quad == 0) {
                    atomicAdd(&cs_sh[lcol], s);
                    atomicAdd(&cq_sh[lcol], q);
                }
            }
        }
    }
    __syncthreads();
    if constexpr (STATS) {
        // depth-limited relaxed atomics: ~GB64/NREP adds per address
        float2* gdst = gsum_out + (size_t)(rb & (NREP - 1)) * C + colB;
        for (int c = t; c < CB; c += 256) {
            atomicAdd(&gdst[c].x, cs_sh[c]);
            atomicAdd(&gdst[c].y, cq_sh[c]);
        }
    }
    // ---- coalesced row-major store ----
    for (int i = t * 4; i < 64 * CB; i += 256 * 4) {
        int r = i / CB, c = i - (i / CB) * CB;
        if (row0 + r < n) {
            float4 v4 = *(const float4*)&cbuf[r * LCB + c];
            if constexpr (__is_same(OutT, float)) {
                *(float4*)&out[(size_t)(row0 + r) * C + colB + c] = v4;
            } else {
                half4_t h4 = { (_Float16)v4.x, (_Float16)v4.y,
                               (_Float16)v4.z, (_Float16)v4.w };
                *(half4_t*)&out[(size_t)(row0 + r) * C + colB + c] = h4;
            }
        }
    }
}

// ---- fused softmax + weighted gather over the GEMM *input* rows ----
template<int C>
__global__ __launch_bounds__(256) void
attn_aggregate(const _Float16* __restrict__ h, const int* __restrict__ srcs,
               const int* __restrict__ ptr, const float* __restrict__ e_n,
               const float* __restrict__ f_n, _Float16* __restrict__ out) {
    constexpr int RL = C / 8;          // lanes per row: 8 (C=64) or 16 (C=128)
    constexpr int G  = 64 / RL;        // row groups per wave: 8 or 4
    int d = blockIdx.x * 4 + (threadIdx.x >> 6);
    if (d >= N_NODES) return;
    int l  = threadIdx.x & 63;
    int b0 = ptr[d], b1 = ptr[d + 1];
    int deg = b1 - b0;
    float fd = f_n[d];
    const int g  = l / RL;
    const int cl = l % RL;
    float acc[8] = {0.f, 0.f, 0.f, 0.f, 0.f, 0.f, 0.f, 0.f};

    if (deg <= 64) {
        int sj = 0; float lg = -1e30f;
        if (l < deg) {
            sj = srcs[b0 + l];
            float v = e_n[sj] + fd;
            lg = v > 0.f ? v : GAT_SLOPE * v;
        }
        float m  = wred_max(lg);
        float e0 = (l < deg) ? __expf(lg - m) : 0.f;
        float ex = e0 / wred_sum(e0);

        int jj = 0;
        for (; jj + 4 * G <= deg; jj += 4 * G) {     // 4 loads in flight / group
            float wk[4]; int sk[4];
#pragma unroll
            for (int k = 0; k < 4; ++k) {
                int j = jj + k * G + g;
                wk[k] = __shfl(ex, j, 64);
                sk[k] = __shfl(sj, j, 64);
            }
            half8_t v[4];
#pragma unroll
            for (int k = 0; k < 4; ++k)
                v[k] = *(const half8_t*)&h[(size_t)sk[k] * C + cl * 8];
#pragma unroll
            for (int k = 0; k < 4; ++k)
#pragma unroll
                for (int i = 0; i < 8; ++i)
                    acc[i] += wk[k] * (float)v[k][i];
        }
        for (; jj + 2 * G <= deg; jj += 2 * G) {
            float w1 = __shfl(ex, jj + g, 64);
            int   s1 = __shfl(sj, jj + g, 64);
            float w2 = __shfl(ex, jj + G + g, 64);
            int   s2 = __shfl(sj, jj + G + g, 64);
            half8_t v1 = *(const half8_t*)&h[(size_t)s1 * C + cl * 8];
            half8_t v2 = *(const half8_t*)&h[(size_t)s2 * C + cl * 8];
#pragma unroll
            for (int i = 0; i < 8; ++i)
                acc[i] += w1 * (float)v1[i] + w2 * (float)v2[i];
        }
        for (; jj < deg; jj += G) {                  // exact tail
            int j = jj + g;
            float wk = __shfl(ex, j, 64);
            int   sk = __shfl(sj, j, 64);
            if (j < deg) {
                half8_t v = *(const half8_t*)&h[(size_t)sk * C + cl * 8];
#pragma unroll
                for (int i = 0; i < 8; ++i) acc[i] += wk * (float)v[i];
            }
        }
    } else {
        float m_l = -1e30f, den_l = 0.f;
        for (int j = b0 + l; j < b1; j += 64) {
            float lg = e_n[srcs[j]] + fd;
            lg = lg > 0.f ? lg : GAT_SLOPE * lg;
            float nm = fmaxf(m_l, lg);
            den_l = den_l * __expf(m_l - nm) + __expf(lg - nm);
            m_l = nm;
        }
        float m = wred_max(m_l);
        float inv = 1.f / wred_sum(den_l * __expf(m_l - m));
        for (int c0 = b0; c0 < b1; c0 += 64) {
            int jl = c0 + l;
            int sj = 0; float ex = 0.f;
            if (jl < b1) {
                sj = srcs[jl];
                float lg = e_n[sj] + fd;
                lg = lg > 0.f ? lg : GAT_SLOPE * lg;
                ex = __expf(lg - m) * inv;
            }
            int nE = min(64, b1 - c0);
            for (int jj = 0; jj < nE; jj += 2 * G) {
                int j1 = jj + g, j2 = jj + G + g;
                float w1 = __shfl(ex, j1, 64);
                int   s1 = __shfl(sj, j1, 64);
                float w2 = __shfl(ex, j2, 64);
                int   s2 = __shfl(sj, j2, 64);
                half8_t v1 = *(const half8_t*)&h[(size_t)s1 * C + cl * 8];
                half8_t v2 = *(const half8_t*)&h[(size_t)s2 * C + cl * 8];
#pragma unroll
                for (int i = 0; i < 8; ++i)
                    acc[i] += w1 * (float)v1[i] + w2 * (float)v2[i];
            }
        }
    }
#pragma unroll
    for (int mm = RL; mm < 64; mm <<= 1)
#pragma unroll
        for (int i = 0; i < 8; ++i) acc[i] += __shfl_xor(acc[i], mm, 64);
    if (g == 0) {
        int c = cl * 8;
        half8_t o;
#pragma unroll
        for (int i = 0; i < 8; ++i) o[i] = (_Float16)acc[i];
        *(half8_t*)&out[(size_t)d * C + c] = o;
    }
}

extern "C" void kernel_launch(void* const* d_in, const int* in_sizes, int n_in,
                              void* d_out, int out_size, void* d_ws, size_t ws_size,
                              hipStream_t stream) {
    const float* emb  = (const float*)d_in[0];
    const int*   ei   = (const int*)  d_in[1];
    const float* W1   = (const float*)d_in[2];
    const float* as1  = (const float*)d_in[3];
    const float* ad1  = (const float*)d_in[4];
    const float* b1   = (const float*)d_in[5];
    const float* g1   = (const float*)d_in[6];
    const float* be1  = (const float*)d_in[7];
    const float* W2   = (const float*)d_in[8];
    const float* as2  = (const float*)d_in[9];
    const float* ad2  = (const float*)d_in[10];
    const float* b2   = (const float*)d_in[11];
    const float* g2   = (const float*)d_in[12];
    const float* be2  = (const float*)d_in[13];
    const float* Wf   = (const float*)d_in[14];
    const float* bf   = (const float*)d_in[15];
    float* out = (float*)d_out;

    char* w = (char*)d_ws;
    auto alloc = [&](size_t bytes) {
        char* p = w;
        w += (bytes + 255) & ~(size_t)255;
        return (void*)p;
    };
    // embh and agg1 are contiguous (each 6.4MB, 256B-aligned) — together they
    // are reused as z1h (12.8MB) after both are dead.
    _Float16* embh = (_Float16*)alloc((size_t)N_NODES * 64 * 2);   // emb fp16
    _Float16* agg1 = (_Float16*)alloc((size_t)N_NODES * 64 * 2);   // layer-1 aggregate
    _Float16* out1 = (_Float16*)alloc((size_t)N_NODES * 128 * 2);  // agg1 @ W1 + b1
    _Float16* agg2 = (_Float16*)alloc((size_t)N_NODES * 128 * 2);  // layer-2 aggregate
    _Float16* out2 = (_Float16*)alloc((size_t)N_NODES * 256 * 2);  // agg2 @ W2 + b2
    _Float16* z1h  = embh;                       // alias: lrelu(bn(out1)), 12.8MB
    unsigned* bedge = (unsigned*)out2;           // alias: bucket edges (4MB), dead
                                                 // before out2 is written
    float*  e_n  = (float*) alloc((size_t)N_NODES * 4);
    float*  f_n  = (float*) alloc((size_t)N_NODES * 4);
    int*    srcs = (int*)   alloc((size_t)N_TOT * 4);
    int*    bcnt = (int*)   alloc((size_t)NBUCK * 4);
    int*    ptr  = (int*)   alloc((size_t)(N_NODES + 1) * 4);
    float2* gsum1 = (float2*)alloc((size_t)NREP * 128 * 8);  // BN1 replicas (8KB)
    float2* gsum2 = (float2*)alloc((size_t)NREP * 256 * 8);  // BN2 replicas (16KB)
    float*  va1  = (float*) alloc(64 * 4);
    float*  vb1  = (float*) alloc(64 * 4);
    float*  va2  = (float*) alloc(128 * 4);
    float*  vb2  = (float*) alloc(128 * 4);
    _Float16* wt1 = (_Float16*)alloc((size_t)64 * 128 * 2);
    _Float16* wt2 = (_Float16*)alloc((size_t)128 * 256 * 2);
    _Float16* wtf = (_Float16*)alloc((size_t)256 * 256 * 2);

    const int RW4 = (N_NODES + 3) / 4;   // wave-per-row grids

    // 1) init: weight fragment-major + a-vec matvecs + counters/replica zero
    init_misc<<<(106496 + 384 + 255) / 256, 256, 0, stream>>>(
        W1, W2, Wf, wt1, wt2, wtf, bcnt, gsum1, gsum2,
        as1, ad1, as2, ad2, va1, vb1, va2, vb2);

    // 2) fused: bucket append (single-pass) ∥ emb cast + layer-1 logits
    append_emb<<<K1_NB + RW4, 256, 0, stream>>>(
        ei, bcnt, bedge, emb, va1, vb1, embh, e_n, f_n);

    // 3) per-bucket CSR
    bucket_csr<<<NBUCK, 256, 0, stream>>>(bcnt, bedge, ptr, srcs);

    // 4) layer-1 aggregate (128B rows)
    attn_aggregate<64><<<RW4, 256, 0, stream>>>(embh, srcs, ptr, e_n, f_n, agg1);

    // 5) GEMM 64->128, BN1 stats -> gsum1 replicas
    gemm_mfma<64, 128, 128, _Float16, true, false><<<GB64, 256, 0, stream>>>(
        agg1, wt1, b1, out1, N_NODES, gsum1, nullptr, nullptr, nullptr);

    // 6) z1 = lrelu(bn1(out1)) (coefs from gsum1 replicas) + layer-2 logits
    ef_dots<<<RW4, 256, 0, stream>>>(out1, gsum1, g1, be1, va2, vb2, z1h, e_n, f_n);

    // 7) layer-2 aggregate (256B rows)
    attn_aggregate<128><<<RW4, 256, 0, stream>>>(z1h, srcs, ptr, e_n, f_n, agg2);

    // 8) GEMM 128->256, BN2 stats -> gsum2 replicas
    gemm_mfma<128, 256, 128, _Float16, true, false><<<GB64 * 2, 256, 0, stream>>>(
        agg2, wt2, b2, out2, N_NODES, gsum2, nullptr, nullptr, nullptr);

    // 9) final linear 256->256, BN2+lrelu from gsum2 replicas in LDS prologue
    gemm_mfma<256, 256, 128, float, false, true><<<GB64 * 2, 256, 0, stream>>>(
        out2, wtf, bf, out, N_NODES, nullptr, gsum2, g2, be2);
}